// Round 6
// baseline (180.810 us; speedup 1.0000x reference)
//
#include <hip/hip_runtime.h>
#include <math.h>

// ---------------------------------------------------------------------------
// HDRL Poincare MLR, c=1.
//   arg = 2*(Bc*xa - Aq*pa) / (Bc*(1-x2)*an),  Aq = 1+x2-2px, Bc = 1-p2
//   out = copysign(asinh(|arg|), arg) * an      (Dd cancels exactly; Dd>0)
// px = <x_b, p_o>, xa = <x_b, a_o> via dual bf16 MFMA GEMM (shared x tiles).
//
// R6: B operands (P,W) bypass LDS — prep packs them fragment-linear
//     (16col x 32K fragment = 64 lanes x 16 B contiguous), main kernel loads
//     B-frags as coalesced dwordx4 global->VGPR (L2-resident via XCD stripe).
//     LDS stages A only (64 KB dbuf). LDS traffic/tile: 256KB -> 96KB, so
//     MFMA (2480cyc) finally exceeds LDS (1130cyc) and VMEM (~1200cyc).
// ---------------------------------------------------------------------------

#define B_DIM 8192
#define O_DIM 4096
#define K_DIM 1024

using f32x4  = __attribute__((ext_vector_type(4))) float;
using bf16x8 = __attribute__((ext_vector_type(8))) short;

__device__ inline unsigned short f2bf(float f) {
  union { float f; unsigned u; } v; v.f = f;
  unsigned u = v.u;
  u += 0x7FFFu + ((u >> 16) & 1u);   // RNE
  return (unsigned short)(u >> 16);
}

__device__ inline void load_lds16(const void* g, void* l) {
  __builtin_amdgcn_global_load_lds(
      (const __attribute__((address_space(1))) void*)g,
      (__attribute__((address_space(3))) void*)l, 16, 0, 0);
}

__device__ inline float frcp(float x)  { float r; asm("v_rcp_f32 %0, %1"  : "=v"(r) : "v"(x)); return r; }
__device__ inline float fsqrt_(float x){ float r; asm("v_sqrt_f32 %0, %1" : "=v"(r) : "v"(x)); return r; }
__device__ inline float flog2(float x) { float r; asm("v_log_f32 %0, %1"  : "=v"(r) : "v"(x)); return r; }

// ---- per-output-row stats + fragment-packed bf16 P/W ----------------------
// Packed layout (elements): frag block fb = (o>>4)*32 + (k>>5), 512 elems:
//   lane = (o&15) + ((k>>3)&3)*16, elem = fb*512 + lane*8 + (k&7).
// A wave reading 64 lanes x 16 B at fb*1024 bytes gets exactly the MFMA
// B-operand fragment for cols [o&~15, +16), k in [k&~31, +32).
__global__ __launch_bounds__(256) void prep_rows(
    const float* __restrict__ wgt, const float* __restrict__ bia,
    unsigned short* __restrict__ w_pk, unsigned short* __restrict__ p_pk,
    float* __restrict__ p2v, float* __restrict__ pav, float* __restrict__ anv)
{
  const int o = blockIdx.x, t = threadIdx.x;
  const float4 w = ((const float4*)(wgt + (size_t)o * K_DIM))[t];
  const float4 b = ((const float4*)(bia + (size_t)o * K_DIM))[t];
  float a2 = w.x*w.x + w.y*w.y + w.z*w.z + w.w*w.w;
  float b2 = b.x*b.x + b.y*b.y + b.z*b.z + b.w*b.w;
  float ab = w.x*b.x + w.y*b.y + w.z*b.z + w.w*b.w;
  #pragma unroll
  for (int off = 32; off; off >>= 1) {
    a2 += __shfl_down(a2, off);
    b2 += __shfl_down(b2, off);
    ab += __shfl_down(ab, off);
  }
  __shared__ float sa[4], sb[4], sc_[4];
  const int wv = t >> 6, ln = t & 63;
  if (ln == 0) { sa[wv] = a2; sb[wv] = b2; sc_[wv] = ab; }
  __syncthreads();
  const float A2 = sa[0] + sa[1] + sa[2] + sa[3];
  const float B2 = sb[0] + sb[1] + sb[2] + sb[3];
  const float AB = sc_[0] + sc_[1] + sc_[2] + sc_[3];
  const float norm = sqrtf(B2);
  const float maxn = 1.0f - 1e-5f;            // (1-PROJ_EPS)/sqrt(c), c=1
  const float s = (norm > maxn) ? (maxn / norm) : 1.0f;
  if (t == 0) { p2v[o] = B2 * s * s; pav[o] = AB * s; anv[o] = sqrtf(A2); }
  // packed write: k = 4t..4t+3 -> same lane chunk, offsets (4t&7)..+3
  const size_t fb  = (size_t)(o >> 4) * 32 + (t >> 3);
  const int    lnp = (o & 15) + ((t >> 1) & 3) * 16;
  const size_t base = fb * 512 + (size_t)lnp * 8 + ((4 * t) & 7);
  w_pk[base + 0] = f2bf(w.x); w_pk[base + 1] = f2bf(w.y);
  w_pk[base + 2] = f2bf(w.z); w_pk[base + 3] = f2bf(w.w);
  p_pk[base + 0] = f2bf(b.x * s); p_pk[base + 1] = f2bf(b.y * s);
  p_pk[base + 2] = f2bf(b.z * s); p_pk[base + 3] = f2bf(b.w * s);
}

// ---- per-batch-row stats + bf16 conversion of x ---------------------------
__global__ __launch_bounds__(256) void prep_x(
    const float* __restrict__ x, unsigned short* __restrict__ x_bf,
    float* __restrict__ x2v)
{
  const int bi = blockIdx.x, t = threadIdx.x;
  const float4 v = ((const float4*)(x + (size_t)bi * K_DIM))[t];
  float s2 = v.x*v.x + v.y*v.y + v.z*v.z + v.w*v.w;
  #pragma unroll
  for (int off = 32; off; off >>= 1) s2 += __shfl_down(s2, off);
  __shared__ float sl[4];
  const int wv = t >> 6, ln = t & 63;
  if (ln == 0) sl[wv] = s2;
  __syncthreads();
  if (t == 0) x2v[bi] = sl[0] + sl[1] + sl[2] + sl[3];
  unsigned short* xo = x_bf + (size_t)bi * K_DIM + t * 4;
  xo[0] = f2bf(v.x); xo[1] = f2bf(v.y); xo[2] = f2bf(v.z); xo[3] = f2bf(v.w);
}

// ---- main dual-GEMM + fused epilogue ---------------------------------------
// 8 waves (4M x 2N). BM=256, BN=128 (dual P/W), BK=64. 16 K-tiles.
// LDS: A only, double-buffered: 2 x 256x64 bf16 = 64 KB.
// B-fragments loaded direct global->VGPR from packed layout (L2-resident).
// One __syncthreads per K-tile (dbuf A staging race-free mid-tile).
__global__ __launch_bounds__(512, 2) void hdrl_main(
    const unsigned short* __restrict__ Xb,
    const unsigned short* __restrict__ Pp,
    const unsigned short* __restrict__ Wp,
    const float* __restrict__ x2v, const float* __restrict__ p2v,
    const float* __restrict__ pav, const float* __restrict__ anv,
    float* __restrict__ out)
{
  extern __shared__ unsigned short lds[];

  const int bid   = blockIdx.x;
  const int xcd   = bid & 7;
  const int local = bid >> 3;                 // 0..127 per XCD
  const int nt    = xcd * 4 + (local & 3);    // 4 n-columns per XCD
  const int mt    = local >> 2;               // 0..31
  const int row0 = mt * 256, col0 = nt * 128;
  const int t    = threadIdx.x;
  const int wv   = t >> 6, lane = t & 63;
  const int wm   = wv >> 1, wn = wv & 1;      // 4M x 2N waves
  const int lrow = lane & 15, kg = lane >> 4;
  const int sw   = (lrow & 7) << 3;           // read-side XOR key (elems)

  // A staging: thread t covers chunk (r = q*64 + (t>>3), c = t&7), 16B chunks
  const int sr   = t >> 3;                    // 0..63
  const int sc   = t & 7;
  const int scol = (sc ^ (sr & 7)) * 8;       // inverse-swizzled source col
  const unsigned short* gA = Xb + (size_t)(row0 + sr) * K_DIM + scol;

  // B packed base: wave's col-tile = col0/16 + wn*4 (+j); elem offsets
  const size_t pbase = ((size_t)((col0 >> 4) + wn * 4) * 32) * 512 + (size_t)lane * 8;

  f32x4 accp[4][4], acca[4][4];
  #pragma unroll
  for (int i = 0; i < 4; ++i)
    #pragma unroll
    for (int j = 0; j < 4; ++j) { accp[i][j] = (f32x4)0.0f; acca[i][j] = (f32x4)0.0f; }

#define STAGE_A(q) load_lds16(gA + (size_t)(q)*64*K_DIM + k0n, (void*)&lds[nb + (q)*4096 + wv*512])

  // prologue: stage A tile 0 into buffer 0
  {
    const int nb = 0, k0n = 0;
    STAGE_A(0); STAGE_A(1); STAGE_A(2); STAGE_A(3);
  }
  __syncthreads();

  int cur = 0;
  for (int kt = 0; kt < 16; ++kt) {
    const int nxt = cur ^ 1;
    const int nb  = nxt * 16384;
    const int cb  = cur * 16384;
    const int k0n = (kt + 1) * 64;

    // 1) stage next A tile (longest slack until the end-of-tile barrier)
    if (kt < 15) { STAGE_A(0); STAGE_A(1); STAGE_A(2); STAGE_A(3); }

    // 2) issue all B-fragment loads for this tile (coalesced dwordx4, L2)
    bf16x8 bp[4][2], bw[4][2];
    #pragma unroll
    for (int j = 0; j < 4; ++j) {
      const size_t jb = pbase + (size_t)j * 16384 + (size_t)(kt * 2) * 512;
      bp[j][0] = *(const bf16x8*)&Pp[jb];
      bp[j][1] = *(const bf16x8*)&Pp[jb + 512];
      bw[j][0] = *(const bf16x8*)&Wp[jb];
      bw[j][1] = *(const bf16x8*)&Wp[jb + 512];
    }

    // 3) A fragments from LDS (swizzled)
    const int kbs0 = (kg * 8) ^ sw;
    const int kbs1 = (32 + kg * 8) ^ sw;
    bf16x8 af[4][2];
    #pragma unroll
    for (int i = 0; i < 4; ++i) {
      af[i][0] = *(const bf16x8*)&lds[cb + (wm*64 + i*16 + lrow)*64 + kbs0];
      af[i][1] = *(const bf16x8*)&lds[cb + (wm*64 + i*16 + lrow)*64 + kbs1];
    }

    // 4) MFMAs (compiler interleaves vmcnt/lgkm waits)
    __builtin_amdgcn_s_setprio(1);
    #pragma unroll
    for (int i = 0; i < 4; ++i)
      #pragma unroll
      for (int j = 0; j < 4; ++j)
        #pragma unroll
        for (int kk = 0; kk < 2; ++kk)
          accp[i][j] = __builtin_amdgcn_mfma_f32_16x16x32_bf16(af[i][kk], bp[j][kk], accp[i][j], 0, 0, 0);
    #pragma unroll
    for (int i = 0; i < 4; ++i)
      #pragma unroll
      for (int j = 0; j < 4; ++j)
        #pragma unroll
        for (int kk = 0; kk < 2; ++kk)
          acca[i][j] = __builtin_amdgcn_mfma_f32_16x16x32_bf16(af[i][kk], bw[j][kk], acca[i][j], 0, 0, 0);
    __builtin_amdgcn_s_setprio(0);

    __syncthreads();   // drains vmcnt+lgkmcnt: next A buffer fully resident
    cur = nxt;
  }

  // fused epilogue: C/D layout col = lane&15, row = (lane>>4)*4 + reg.
  // arg = 2*(Bc*xa - Aq*pa) / (Bc*(1-x2)*an); out = copysign(asinh|arg|,arg)*an
  float Bcj[4], paj[4], dja[4], lcj[4];
  #pragma unroll
  for (int j = 0; j < 4; ++j) {
    const int col = col0 + wn * 64 + j * 16 + lrow;
    const float Bc = 1.0f - p2v[col];
    const float an = anv[col];
    Bcj[j] = Bc; paj[j] = pav[col];
    dja[j] = Bc * an;                 // denom col factor
    lcj[j] = 0.69314718f * an;        // ln2 * a_norm
  }
  #pragma unroll
  for (int i = 0; i < 4; ++i) {
    const int rbase = row0 + wm * 64 + i * 16 + kg * 4;
    #pragma unroll
    for (int r = 0; r < 4; ++r) {
      const int row = rbase + r;
      const float x2 = x2v[row];
      const float Aqh = 1.0f + x2;
      const float omx = 1.0f - x2;
      float* orow = out + (size_t)row * O_DIM + col0 + wn * 64 + lrow;
      #pragma unroll
      for (int j = 0; j < 4; ++j) {
        const float px = accp[i][j][r];
        const float xa = acca[i][j][r];
        const float numer = Bcj[j] * xa - (Aqh - 2.0f * px) * paj[j];
        const float denom = dja[j] * omx + 1e-15f;
        const float arg = 2.0f * numer * frcp(denom);
        const float aa  = fabsf(arg);
        const float u   = aa + fsqrt_(__builtin_fmaf(aa, aa, 1.0f));
        orow[j * 16] = copysignf(flog2(u) * lcj[j], arg);
      }
    }
  }
#undef STAGE_A
}

extern "C" void kernel_launch(void* const* d_in, const int* in_sizes, int n_in,
                              void* d_out, int out_size, void* d_ws, size_t ws_size,
                              hipStream_t stream) {
  (void)in_sizes; (void)n_in; (void)out_size; (void)ws_size;
  const float* x = (const float*)d_in[0];
  const float* w = (const float*)d_in[1];
  const float* b = (const float*)d_in[2];
  float* out = (float*)d_out;

  char* ws = (char*)d_ws;
  unsigned short* x_bf = (unsigned short*)ws;                               // 16 MB
  unsigned short* p_pk = (unsigned short*)(ws + (size_t)16 * 1024 * 1024);  //  8 MB
  unsigned short* w_pk = (unsigned short*)(ws + (size_t)24 * 1024 * 1024);  //  8 MB
  float* p2v = (float*)(ws + (size_t)32 * 1024 * 1024);
  float* pav = p2v + O_DIM;
  float* anv = pav + O_DIM;
  float* x2v = anv + O_DIM;

  prep_rows<<<O_DIM, 256, 0, stream>>>(w, b, w_pk, p_pk, p2v, pav, anv);
  prep_x<<<B_DIM, 256, 0, stream>>>(x, x_bf, x2v);

  hipFuncSetAttribute((const void*)hdrl_main,
                      hipFuncAttributeMaxDynamicSharedMemorySize, 65536);
  const int grid = (B_DIM / 256) * (O_DIM / 128);   // 1024
  hdrl_main<<<grid, 512, 65536, stream>>>(x_bf, p_pk, w_pk, x2v, p2v, pav, anv, out);
}

// Round 7
// 179.964 us; speedup vs baseline: 1.0047x; 1.0047x over previous
//
#include <hip/hip_runtime.h>
#include <math.h>

// ---------------------------------------------------------------------------
// HDRL Poincare MLR, c=1.
//   arg = 2*(Bc*xa - Aq*pa) / (Bc*(1-x2)*an),  Aq = 1+x2-2px, Bc = 1-p2
//   out = copysign(asinh(|arg|), arg) * an      (Dd cancels exactly; Dd>0)
// px = <x_b, p_o>, xa = <x_b, a_o> via dual bf16 MFMA GEMM (shared x tiles).
//
// R6: B operands (P,W) bypass LDS — prep packs them fragment-linear
//     (16col x 32K fragment = 64 lanes x 16 B contiguous), main kernel loads
//     B-frags as coalesced dwordx4 global->VGPR (L2-resident via XCD stripe).
//     LDS stages A only (64 KB dbuf). LDS traffic/tile: 256KB -> 96KB, so
//     MFMA (2480cyc) finally exceeds LDS (1130cyc) and VMEM (~1200cyc).
// ---------------------------------------------------------------------------

#define B_DIM 8192
#define O_DIM 4096
#define K_DIM 1024

using f32x4  = __attribute__((ext_vector_type(4))) float;
using bf16x8 = __attribute__((ext_vector_type(8))) short;

__device__ inline unsigned short f2bf(float f) {
  union { float f; unsigned u; } v; v.f = f;
  unsigned u = v.u;
  u += 0x7FFFu + ((u >> 16) & 1u);   // RNE
  return (unsigned short)(u >> 16);
}

__device__ inline void load_lds16(const void* g, void* l) {
  __builtin_amdgcn_global_load_lds(
      (const __attribute__((address_space(1))) void*)g,
      (__attribute__((address_space(3))) void*)l, 16, 0, 0);
}

__device__ inline float frcp(float x)  { float r; asm("v_rcp_f32 %0, %1"  : "=v"(r) : "v"(x)); return r; }
__device__ inline float fsqrt_(float x){ float r; asm("v_sqrt_f32 %0, %1" : "=v"(r) : "v"(x)); return r; }
__device__ inline float flog2(float x) { float r; asm("v_log_f32 %0, %1"  : "=v"(r) : "v"(x)); return r; }

// ---- per-output-row stats + fragment-packed bf16 P/W ----------------------
// Packed layout (elements): frag block fb = (o>>4)*32 + (k>>5), 512 elems:
//   lane = (o&15) + ((k>>3)&3)*16, elem = fb*512 + lane*8 + (k&7).
// A wave reading 64 lanes x 16 B at fb*1024 bytes gets exactly the MFMA
// B-operand fragment for cols [o&~15, +16), k in [k&~31, +32).
__global__ __launch_bounds__(256) void prep_rows(
    const float* __restrict__ wgt, const float* __restrict__ bia,
    unsigned short* __restrict__ w_pk, unsigned short* __restrict__ p_pk,
    float* __restrict__ p2v, float* __restrict__ pav, float* __restrict__ anv)
{
  const int o = blockIdx.x, t = threadIdx.x;
  const float4 w = ((const float4*)(wgt + (size_t)o * K_DIM))[t];
  const float4 b = ((const float4*)(bia + (size_t)o * K_DIM))[t];
  float a2 = w.x*w.x + w.y*w.y + w.z*w.z + w.w*w.w;
  float b2 = b.x*b.x + b.y*b.y + b.z*b.z + b.w*b.w;
  float ab = w.x*b.x + w.y*b.y + w.z*b.z + w.w*b.w;
  #pragma unroll
  for (int off = 32; off; off >>= 1) {
    a2 += __shfl_down(a2, off);
    b2 += __shfl_down(b2, off);
    ab += __shfl_down(ab, off);
  }
  __shared__ float sa[4], sb[4], sc_[4];
  const int wv = t >> 6, ln = t & 63;
  if (ln == 0) { sa[wv] = a2; sb[wv] = b2; sc_[wv] = ab; }
  __syncthreads();
  const float A2 = sa[0] + sa[1] + sa[2] + sa[3];
  const float B2 = sb[0] + sb[1] + sb[2] + sb[3];
  const float AB = sc_[0] + sc_[1] + sc_[2] + sc_[3];
  const float norm = sqrtf(B2);
  const float maxn = 1.0f - 1e-5f;            // (1-PROJ_EPS)/sqrt(c), c=1
  const float s = (norm > maxn) ? (maxn / norm) : 1.0f;
  if (t == 0) { p2v[o] = B2 * s * s; pav[o] = AB * s; anv[o] = sqrtf(A2); }
  // packed write: k = 4t..4t+3 -> same lane chunk, offsets (4t&7)..+3
  const size_t fb  = (size_t)(o >> 4) * 32 + (t >> 3);
  const int    lnp = (o & 15) + ((t >> 1) & 3) * 16;
  const size_t base = fb * 512 + (size_t)lnp * 8 + ((4 * t) & 7);
  w_pk[base + 0] = f2bf(w.x); w_pk[base + 1] = f2bf(w.y);
  w_pk[base + 2] = f2bf(w.z); w_pk[base + 3] = f2bf(w.w);
  p_pk[base + 0] = f2bf(b.x * s); p_pk[base + 1] = f2bf(b.y * s);
  p_pk[base + 2] = f2bf(b.z * s); p_pk[base + 3] = f2bf(b.w * s);
}

// ---- per-batch-row stats + bf16 conversion of x ---------------------------
__global__ __launch_bounds__(256) void prep_x(
    const float* __restrict__ x, unsigned short* __restrict__ x_bf,
    float* __restrict__ x2v)
{
  const int bi = blockIdx.x, t = threadIdx.x;
  const float4 v = ((const float4*)(x + (size_t)bi * K_DIM))[t];
  float s2 = v.x*v.x + v.y*v.y + v.z*v.z + v.w*v.w;
  #pragma unroll
  for (int off = 32; off; off >>= 1) s2 += __shfl_down(s2, off);
  __shared__ float sl[4];
  const int wv = t >> 6, ln = t & 63;
  if (ln == 0) sl[wv] = s2;
  __syncthreads();
  if (t == 0) x2v[bi] = sl[0] + sl[1] + sl[2] + sl[3];
  unsigned short* xo = x_bf + (size_t)bi * K_DIM + t * 4;
  xo[0] = f2bf(v.x); xo[1] = f2bf(v.y); xo[2] = f2bf(v.z); xo[3] = f2bf(v.w);
}

// ---- main dual-GEMM + fused epilogue ---------------------------------------
// 8 waves (4M x 2N). BM=256, BN=128 (dual P/W), BK=64. 16 K-tiles.
// LDS: A only, double-buffered: 2 x 256x64 bf16 = 64 KB.
// B-fragments loaded direct global->VGPR from packed layout (L2-resident).
// One __syncthreads per K-tile (dbuf A staging race-free mid-tile).
__global__ __launch_bounds__(512, 2) void hdrl_main(
    const unsigned short* __restrict__ Xb,
    const unsigned short* __restrict__ Pp,
    const unsigned short* __restrict__ Wp,
    const float* __restrict__ x2v, const float* __restrict__ p2v,
    const float* __restrict__ pav, const float* __restrict__ anv,
    float* __restrict__ out)
{
  extern __shared__ unsigned short lds[];

  const int bid   = blockIdx.x;
  const int xcd   = bid & 7;
  const int local = bid >> 3;                 // 0..127 per XCD
  const int nt    = xcd * 4 + (local & 3);    // 4 n-columns per XCD
  const int mt    = local >> 2;               // 0..31
  const int row0 = mt * 256, col0 = nt * 128;
  const int t    = threadIdx.x;
  const int wv   = t >> 6, lane = t & 63;
  const int wm   = wv >> 1, wn = wv & 1;      // 4M x 2N waves
  const int lrow = lane & 15, kg = lane >> 4;
  const int sw   = (lrow & 7) << 3;           // read-side XOR key (elems)

  // A staging: thread t covers chunk (r = q*64 + (t>>3), c = t&7), 16B chunks
  const int sr   = t >> 3;                    // 0..63
  const int sc   = t & 7;
  const int scol = (sc ^ (sr & 7)) * 8;       // inverse-swizzled source col
  const unsigned short* gA = Xb + (size_t)(row0 + sr) * K_DIM + scol;

  // B packed base: wave's col-tile = col0/16 + wn*4 (+j); elem offsets
  const size_t pbase = ((size_t)((col0 >> 4) + wn * 4) * 32) * 512 + (size_t)lane * 8;

  f32x4 accp[4][4], acca[4][4];
  #pragma unroll
  for (int i = 0; i < 4; ++i)
    #pragma unroll
    for (int j = 0; j < 4; ++j) { accp[i][j] = (f32x4)0.0f; acca[i][j] = (f32x4)0.0f; }

#define STAGE_A(q) load_lds16(gA + (size_t)(q)*64*K_DIM + k0n, (void*)&lds[nb + (q)*4096 + wv*512])

  // prologue: stage A tile 0 into buffer 0
  {
    const int nb = 0, k0n = 0;
    STAGE_A(0); STAGE_A(1); STAGE_A(2); STAGE_A(3);
  }
  __syncthreads();

  int cur = 0;
  for (int kt = 0; kt < 16; ++kt) {
    const int nxt = cur ^ 1;
    const int nb  = nxt * 16384;
    const int cb  = cur * 16384;
    const int k0n = (kt + 1) * 64;

    // 1) stage next A tile (longest slack until the end-of-tile barrier)
    if (kt < 15) { STAGE_A(0); STAGE_A(1); STAGE_A(2); STAGE_A(3); }

    // 2) issue all B-fragment loads for this tile (coalesced dwordx4, L2)
    bf16x8 bp[4][2], bw[4][2];
    #pragma unroll
    for (int j = 0; j < 4; ++j) {
      const size_t jb = pbase + (size_t)j * 16384 + (size_t)(kt * 2) * 512;
      bp[j][0] = *(const bf16x8*)&Pp[jb];
      bp[j][1] = *(const bf16x8*)&Pp[jb + 512];
      bw[j][0] = *(const bf16x8*)&Wp[jb];
      bw[j][1] = *(const bf16x8*)&Wp[jb + 512];
    }

    // 3) A fragments from LDS (swizzled)
    const int kbs0 = (kg * 8) ^ sw;
    const int kbs1 = (32 + kg * 8) ^ sw;
    bf16x8 af[4][2];
    #pragma unroll
    for (int i = 0; i < 4; ++i) {
      af[i][0] = *(const bf16x8*)&lds[cb + (wm*64 + i*16 + lrow)*64 + kbs0];
      af[i][1] = *(const bf16x8*)&lds[cb + (wm*64 + i*16 + lrow)*64 + kbs1];
    }

    // 4) MFMAs (compiler interleaves vmcnt/lgkm waits)
    __builtin_amdgcn_s_setprio(1);
    #pragma unroll
    for (int i = 0; i < 4; ++i)
      #pragma unroll
      for (int j = 0; j < 4; ++j)
        #pragma unroll
        for (int kk = 0; kk < 2; ++kk)
          accp[i][j] = __builtin_amdgcn_mfma_f32_16x16x32_bf16(af[i][kk], bp[j][kk], accp[i][j], 0, 0, 0);
    #pragma unroll
    for (int i = 0; i < 4; ++i)
      #pragma unroll
      for (int j = 0; j < 4; ++j)
        #pragma unroll
        for (int kk = 0; kk < 2; ++kk)
          acca[i][j] = __builtin_amdgcn_mfma_f32_16x16x32_bf16(af[i][kk], bw[j][kk], acca[i][j], 0, 0, 0);
    __builtin_amdgcn_s_setprio(0);

    __syncthreads();   // drains vmcnt+lgkmcnt: next A buffer fully resident
    cur = nxt;
  }

  // fused epilogue: C/D layout col = lane&15, row = (lane>>4)*4 + reg.
  // arg = 2*(Bc*xa - Aq*pa) / (Bc*(1-x2)*an); out = copysign(asinh|arg|,arg)*an
  float Bcj[4], paj[4], dja[4], lcj[4];
  #pragma unroll
  for (int j = 0; j < 4; ++j) {
    const int col = col0 + wn * 64 + j * 16 + lrow;
    const float Bc = 1.0f - p2v[col];
    const float an = anv[col];
    Bcj[j] = Bc; paj[j] = pav[col];
    dja[j] = Bc * an;                 // denom col factor
    lcj[j] = 0.69314718f * an;        // ln2 * a_norm
  }
  #pragma unroll
  for (int i = 0; i < 4; ++i) {
    const int rbase = row0 + wm * 64 + i * 16 + kg * 4;
    #pragma unroll
    for (int r = 0; r < 4; ++r) {
      const int row = rbase + r;
      const float x2 = x2v[row];
      const float Aqh = 1.0f + x2;
      const float omx = 1.0f - x2;
      float* orow = out + (size_t)row * O_DIM + col0 + wn * 64 + lrow;
      #pragma unroll
      for (int j = 0; j < 4; ++j) {
        const float px = accp[i][j][r];
        const float xa = acca[i][j][r];
        const float numer = Bcj[j] * xa - (Aqh - 2.0f * px) * paj[j];
        const float denom = dja[j] * omx + 1e-15f;
        const float arg = 2.0f * numer * frcp(denom);
        const float aa  = fabsf(arg);
        const float u   = aa + fsqrt_(__builtin_fmaf(aa, aa, 1.0f));
        orow[j * 16] = copysignf(flog2(u) * lcj[j], arg);
      }
    }
  }
#undef STAGE_A
}

extern "C" void kernel_launch(void* const* d_in, const int* in_sizes, int n_in,
                              void* d_out, int out_size, void* d_ws, size_t ws_size,
                              hipStream_t stream) {
  (void)in_sizes; (void)n_in; (void)out_size; (void)ws_size;
  const float* x = (const float*)d_in[0];
  const float* w = (const float*)d_in[1];
  const float* b = (const float*)d_in[2];
  float* out = (float*)d_out;

  char* ws = (char*)d_ws;
  unsigned short* x_bf = (unsigned short*)ws;                               // 16 MB
  unsigned short* p_pk = (unsigned short*)(ws + (size_t)16 * 1024 * 1024);  //  8 MB
  unsigned short* w_pk = (unsigned short*)(ws + (size_t)24 * 1024 * 1024);  //  8 MB
  float* p2v = (float*)(ws + (size_t)32 * 1024 * 1024);
  float* pav = p2v + O_DIM;
  float* anv = pav + O_DIM;
  float* x2v = anv + O_DIM;

  prep_rows<<<O_DIM, 256, 0, stream>>>(w, b, w_pk, p_pk, p2v, pav, anv);
  prep_x<<<B_DIM, 256, 0, stream>>>(x, x_bf, x2v);

  hipFuncSetAttribute((const void*)hdrl_main,
                      hipFuncAttributeMaxDynamicSharedMemorySize, 65536);
  const int grid = (B_DIM / 256) * (O_DIM / 128);   // 1024
  hdrl_main<<<grid, 512, 65536, stream>>>(x_bf, p_pk, w_pk, x2v, p2v, pav, anv, out);
}

// Round 8
// 148.058 us; speedup vs baseline: 1.2212x; 1.2155x over previous
//
#include <hip/hip_runtime.h>
#include <math.h>

// ---------------------------------------------------------------------------
// HDRL Poincare MLR, c=1.
//   arg = 2*(Bc*xa - Aq*pa) / (Bc*(1-x2)*an),  Aq = 1+x2-2px, Bc = 1-p2
//   out = copysign(asinh(|arg|), arg) * an      (Dd cancels exactly; Dd>0)
// px = <x_b, p_o>, xa = <x_b, a_o> via dual bf16 MFMA GEMM (shared x tiles).
//
// R7: revert R6's B-bypass (L2 at 56B/cyc/CU is a WORSE B-path than the LDS
//     port at 85-128B/cyc + exposed latency). Back to R5 structure, plus
//     T19 sched_group_barrier interleave: stream per K-tile =
//     [12 DS_READ][4 DS_READ | 16 MFMA] x4 — overlaps the CU's LDS port
//     time (~3000cyc) with MFMA pipe time (~2480cyc) instead of
//     serializing them (R5's hoisted-read phase gave 43.6% MfmaUtil).
// ---------------------------------------------------------------------------

#define B_DIM 8192
#define O_DIM 4096
#define K_DIM 1024

using f32x4  = __attribute__((ext_vector_type(4))) float;
using bf16x8 = __attribute__((ext_vector_type(8))) short;

__device__ inline unsigned short f2bf(float f) {
  union { float f; unsigned u; } v; v.f = f;
  unsigned u = v.u;
  u += 0x7FFFu + ((u >> 16) & 1u);   // RNE
  return (unsigned short)(u >> 16);
}

__device__ inline void load_lds16(const void* g, void* l) {
  __builtin_amdgcn_global_load_lds(
      (const __attribute__((address_space(1))) void*)g,
      (__attribute__((address_space(3))) void*)l, 16, 0, 0);
}

__device__ inline float frcp(float x)  { float r; asm("v_rcp_f32 %0, %1"  : "=v"(r) : "v"(x)); return r; }
__device__ inline float fsqrt_(float x){ float r; asm("v_sqrt_f32 %0, %1" : "=v"(r) : "v"(x)); return r; }
__device__ inline float flog2(float x) { float r; asm("v_log_f32 %0, %1"  : "=v"(r) : "v"(x)); return r; }

// ---- per-output-row stats + bf16 conversion (weight & projected bias) -----
__global__ __launch_bounds__(256) void prep_rows(
    const float* __restrict__ wgt, const float* __restrict__ bia,
    unsigned short* __restrict__ a_bf, unsigned short* __restrict__ p_bf,
    float* __restrict__ p2v, float* __restrict__ pav, float* __restrict__ anv)
{
  const int o = blockIdx.x, t = threadIdx.x;
  const float4 w = ((const float4*)(wgt + (size_t)o * K_DIM))[t];
  const float4 b = ((const float4*)(bia + (size_t)o * K_DIM))[t];
  float a2 = w.x*w.x + w.y*w.y + w.z*w.z + w.w*w.w;
  float b2 = b.x*b.x + b.y*b.y + b.z*b.z + b.w*b.w;
  float ab = w.x*b.x + w.y*b.y + w.z*b.z + w.w*b.w;
  #pragma unroll
  for (int off = 32; off; off >>= 1) {
    a2 += __shfl_down(a2, off);
    b2 += __shfl_down(b2, off);
    ab += __shfl_down(ab, off);
  }
  __shared__ float sa[4], sb[4], sc_[4];
  const int wv = t >> 6, ln = t & 63;
  if (ln == 0) { sa[wv] = a2; sb[wv] = b2; sc_[wv] = ab; }
  __syncthreads();
  const float A2 = sa[0] + sa[1] + sa[2] + sa[3];
  const float B2 = sb[0] + sb[1] + sb[2] + sb[3];
  const float AB = sc_[0] + sc_[1] + sc_[2] + sc_[3];
  const float norm = sqrtf(B2);
  const float maxn = 1.0f - 1e-5f;            // (1-PROJ_EPS)/sqrt(c), c=1
  const float s = (norm > maxn) ? (maxn / norm) : 1.0f;
  if (t == 0) { p2v[o] = B2 * s * s; pav[o] = AB * s; anv[o] = sqrtf(A2); }
  unsigned short* ao = a_bf + (size_t)o * K_DIM + t * 4;
  unsigned short* po = p_bf + (size_t)o * K_DIM + t * 4;
  ao[0] = f2bf(w.x); ao[1] = f2bf(w.y); ao[2] = f2bf(w.z); ao[3] = f2bf(w.w);
  po[0] = f2bf(b.x * s); po[1] = f2bf(b.y * s); po[2] = f2bf(b.z * s); po[3] = f2bf(b.w * s);
}

// ---- per-batch-row stats + bf16 conversion of x ---------------------------
__global__ __launch_bounds__(256) void prep_x(
    const float* __restrict__ x, unsigned short* __restrict__ x_bf,
    float* __restrict__ x2v)
{
  const int bi = blockIdx.x, t = threadIdx.x;
  const float4 v = ((const float4*)(x + (size_t)bi * K_DIM))[t];
  float s2 = v.x*v.x + v.y*v.y + v.z*v.z + v.w*v.w;
  #pragma unroll
  for (int off = 32; off; off >>= 1) s2 += __shfl_down(s2, off);
  __shared__ float sl[4];
  const int wv = t >> 6, ln = t & 63;
  if (ln == 0) sl[wv] = s2;
  __syncthreads();
  if (t == 0) x2v[bi] = sl[0] + sl[1] + sl[2] + sl[3];
  unsigned short* xo = x_bf + (size_t)bi * K_DIM + t * 4;
  xo[0] = f2bf(v.x); xo[1] = f2bf(v.y); xo[2] = f2bf(v.z); xo[3] = f2bf(v.w);
}

// ---- main dual-GEMM + fused epilogue ---------------------------------------
// 8 waves (4M x 2N). BM=256, BN=128 (dual P/W), BK=64. 16 K-tiles.
// LDS per buffer (bf16 elems): A[256*64]=16384 @0, P[128*64]=8192 @16384,
// W[128*64]=8192 @24576; buffer stride 32768 elems; 2 buffers = 128 KB.
// XCD column-stripe: xcd = bid&7 owns nt in [xcd*4, xcd*4+4).
// One __syncthreads per K-tile; T19 SGB pins [DS4|MFMA16] chunk interleave.
__global__ __launch_bounds__(512, 2) void hdrl_main(
    const unsigned short* __restrict__ Xb,
    const unsigned short* __restrict__ Pb,
    const unsigned short* __restrict__ Ab,
    const float* __restrict__ x2v, const float* __restrict__ p2v,
    const float* __restrict__ pav, const float* __restrict__ anv,
    float* __restrict__ out)
{
  extern __shared__ unsigned short lds[];

  const int bid   = blockIdx.x;
  const int xcd   = bid & 7;
  const int local = bid >> 3;                 // 0..127 per XCD
  const int nt    = xcd * 4 + (local & 3);    // 4 n-columns per XCD
  const int mt    = local >> 2;               // 0..31
  const int row0 = mt * 256, col0 = nt * 128;
  const int t    = threadIdx.x;
  const int wv   = t >> 6, lane = t & 63;
  const int wm   = wv >> 1, wn = wv & 1;      // 4M x 2N waves
  const int lrow = lane & 15, kg = lane >> 4;
  const int sw   = (lrow & 7) << 3;           // read-side XOR key (elems)

  // staging: thread t covers chunk (r = q*64 + (t>>3), c = t&7), 16B chunks
  const int sr   = t >> 3;                    // 0..63
  const int sc   = t & 7;
  const int scol = (sc ^ (sr & 7)) * 8;       // inverse-swizzled source col
  const unsigned short* gA = Xb + (size_t)(row0 + sr) * K_DIM + scol;
  const unsigned short* gP = Pb + (size_t)(col0 + sr) * K_DIM + scol;
  const unsigned short* gW = Ab + (size_t)(col0 + sr) * K_DIM + scol;

  f32x4 accp[4][4], acca[4][4];
  #pragma unroll
  for (int i = 0; i < 4; ++i)
    #pragma unroll
    for (int j = 0; j < 4; ++j) { accp[i][j] = (f32x4)0.0f; acca[i][j] = (f32x4)0.0f; }

#define STAGE_A(q) load_lds16(gA + (size_t)(q)*64*K_DIM + k0n, (void*)&lds[nb + (q)*4096 + wv*512])
#define STAGE_P(q) load_lds16(gP + (size_t)(q)*64*K_DIM + k0n, (void*)&lds[nb + 16384 + (q)*4096 + wv*512])
#define STAGE_W(q) load_lds16(gW + (size_t)(q)*64*K_DIM + k0n, (void*)&lds[nb + 24576 + (q)*4096 + wv*512])

  // prologue: stage tile 0 into buffer 0
  {
    const int nb = 0, k0n = 0;
    STAGE_A(0); STAGE_A(1); STAGE_A(2); STAGE_A(3);
    STAGE_P(0); STAGE_P(1); STAGE_W(0); STAGE_W(1);
  }
  __syncthreads();

  int cur = 0;
  for (int kt = 0; kt < 16; ++kt) {
    const int nxt = cur ^ 1;
    const int nb  = nxt * 32768;
    const int cb  = cur * 32768;
    const int k0n = (kt + 1) * 64;

    // stage next tile first: loads get the whole compute phase to land
    if (kt < 15) {
      STAGE_A(0); STAGE_A(1); STAGE_A(2); STAGE_A(3);
      STAGE_P(0); STAGE_P(1); STAGE_W(0); STAGE_W(1);
    }

    const int kbs0 = (kg * 8) ^ sw;
    const int kbs1 = (32 + kg * 8) ^ sw;
    bf16x8 af[4][2], bp[4][2], bw[4][2];
    #pragma unroll
    for (int i = 0; i < 4; ++i) {
      af[i][0] = *(const bf16x8*)&lds[cb + (wm*64 + i*16 + lrow)*64 + kbs0];
      af[i][1] = *(const bf16x8*)&lds[cb + (wm*64 + i*16 + lrow)*64 + kbs1];
    }
    bp[0][0] = *(const bf16x8*)&lds[cb + 16384 + (wn*64 + 0*16 + lrow)*64 + kbs0];
    bp[0][1] = *(const bf16x8*)&lds[cb + 16384 + (wn*64 + 0*16 + lrow)*64 + kbs1];
    bw[0][0] = *(const bf16x8*)&lds[cb + 24576 + (wn*64 + 0*16 + lrow)*64 + kbs0];
    bw[0][1] = *(const bf16x8*)&lds[cb + 24576 + (wn*64 + 0*16 + lrow)*64 + kbs1];
    // pin: the 12 warm-up DS_READs stay ahead of the MFMA stream
    __builtin_amdgcn_sched_group_barrier(0x100, 12, 0);   // DS_READ x12

    __builtin_amdgcn_s_setprio(1);
    #pragma unroll
    for (int j = 0; j < 4; ++j) {
      if (j < 3) {   // prefetch next j's B frags (4 DS_READ)
        bp[j+1][0] = *(const bf16x8*)&lds[cb + 16384 + (wn*64 + (j+1)*16 + lrow)*64 + kbs0];
        bp[j+1][1] = *(const bf16x8*)&lds[cb + 16384 + (wn*64 + (j+1)*16 + lrow)*64 + kbs1];
        bw[j+1][0] = *(const bf16x8*)&lds[cb + 24576 + (wn*64 + (j+1)*16 + lrow)*64 + kbs0];
        bw[j+1][1] = *(const bf16x8*)&lds[cb + 24576 + (wn*64 + (j+1)*16 + lrow)*64 + kbs1];
      }
      #pragma unroll
      for (int i = 0; i < 4; ++i)
        #pragma unroll
        for (int kk = 0; kk < 2; ++kk)
          accp[i][j] = __builtin_amdgcn_mfma_f32_16x16x32_bf16(af[i][kk], bp[j][kk], accp[i][j], 0, 0, 0);
      #pragma unroll
      for (int i = 0; i < 4; ++i)
        #pragma unroll
        for (int kk = 0; kk < 2; ++kk)
          acca[i][j] = __builtin_amdgcn_mfma_f32_16x16x32_bf16(af[i][kk], bw[j][kk], acca[i][j], 0, 0, 0);
      // target stream per chunk: 4 DS_READ (next j) then 16 MFMA (this j)
      if (j < 3) __builtin_amdgcn_sched_group_barrier(0x100, 4, 0);  // DS_READ x4
      __builtin_amdgcn_sched_group_barrier(0x8, 16, 0);              // MFMA x16
    }
    __builtin_amdgcn_s_setprio(0);

    __syncthreads();   // drains vmcnt+lgkmcnt: next buffer fully resident
    cur = nxt;
  }

  // fused epilogue: C/D layout col = lane&15, row = (lane>>4)*4 + reg.
  // arg = 2*(Bc*xa - Aq*pa) / (Bc*(1-x2)*an); out = copysign(asinh|arg|,arg)*an
  float Bcj[4], paj[4], dja[4], lcj[4];
  #pragma unroll
  for (int j = 0; j < 4; ++j) {
    const int col = col0 + wn * 64 + j * 16 + lrow;
    const float Bc = 1.0f - p2v[col];
    const float an = anv[col];
    Bcj[j] = Bc; paj[j] = pav[col];
    dja[j] = Bc * an;                 // denom col factor
    lcj[j] = 0.69314718f * an;        // ln2 * a_norm
  }
  #pragma unroll
  for (int i = 0; i < 4; ++i) {
    const int rbase = row0 + wm * 64 + i * 16 + kg * 4;
    #pragma unroll
    for (int r = 0; r < 4; ++r) {
      const int row = rbase + r;
      const float x2 = x2v[row];
      const float Aqh = 1.0f + x2;
      const float omx = 1.0f - x2;
      float* orow = out + (size_t)row * O_DIM + col0 + wn * 64 + lrow;
      #pragma unroll
      for (int j = 0; j < 4; ++j) {
        const float px = accp[i][j][r];
        const float xa = acca[i][j][r];
        const float numer = Bcj[j] * xa - (Aqh - 2.0f * px) * paj[j];
        const float denom = dja[j] * omx + 1e-15f;
        const float arg = 2.0f * numer * frcp(denom);
        const float aa  = fabsf(arg);
        const float u   = aa + fsqrt_(__builtin_fmaf(aa, aa, 1.0f));
        orow[j * 16] = copysignf(flog2(u) * lcj[j], arg);
      }
    }
  }
#undef STAGE_A
#undef STAGE_P
#undef STAGE_W
}

extern "C" void kernel_launch(void* const* d_in, const int* in_sizes, int n_in,
                              void* d_out, int out_size, void* d_ws, size_t ws_size,
                              hipStream_t stream) {
  (void)in_sizes; (void)n_in; (void)out_size; (void)ws_size;
  const float* x = (const float*)d_in[0];
  const float* w = (const float*)d_in[1];
  const float* b = (const float*)d_in[2];
  float* out = (float*)d_out;

  char* ws = (char*)d_ws;
  unsigned short* x_bf = (unsigned short*)ws;                               // 16 MB
  unsigned short* p_bf = (unsigned short*)(ws + (size_t)16 * 1024 * 1024);  //  8 MB
  unsigned short* a_bf = (unsigned short*)(ws + (size_t)24 * 1024 * 1024);  //  8 MB
  float* p2v = (float*)(ws + (size_t)32 * 1024 * 1024);
  float* pav = p2v + O_DIM;
  float* anv = pav + O_DIM;
  float* x2v = anv + O_DIM;

  prep_rows<<<O_DIM, 256, 0, stream>>>(w, b, a_bf, p_bf, p2v, pav, anv);
  prep_x<<<B_DIM, 256, 0, stream>>>(x, x_bf, x2v);

  hipFuncSetAttribute((const void*)hdrl_main,
                      hipFuncAttributeMaxDynamicSharedMemorySize, 131072);
  const int grid = (B_DIM / 256) * (O_DIM / 128);   // 1024
  hdrl_main<<<grid, 512, 131072, stream>>>(x_bf, p_bf, a_bf, x2v, p2v, pav, anv, out);
}